// Round 13
// baseline (905.323 us; speedup 1.0000x reference)
//
#include <hip/hip_runtime.h>

typedef __bf16 bf16;
typedef __bf16 bf16x8 __attribute__((ext_vector_type(8)));
typedef float f32x4 __attribute__((ext_vector_type(4)));

#define N_NODES 1024
#define DC 64
#define FREQ 42
#define TREC 41
#define NB 8
#define MAXK 11
#define NSTEP 12
#define SLICE 65536

// ---------------- adjacency prep ----------------
__global__ void transpose_k(const float* __restrict__ in, float* __restrict__ out) {
  __shared__ float tile[32][33];
  int bx = blockIdx.x * 32, by = blockIdx.y * 32;
  int x = threadIdx.x, y = threadIdx.y;
#pragma unroll
  for (int j = 0; j < 32; j += 8) tile[y + j][x] = in[(size_t)(by + y + j) * N_NODES + bx + x];
  __syncthreads();
#pragma unroll
  for (int j = 0; j < 32; j += 8) out[(size_t)(bx + y + j) * N_NODES + by + x] = tile[x][y + j];
}

__global__ void rowsum_k(const float* __restrict__ m, float* __restrict__ sums) {
  int v = blockIdx.x;
  float s = 0.f;
  for (int n = threadIdx.x; n < N_NODES; n += 256) s += m[(size_t)v * N_NODES + n];
  __shared__ float red[256];
  red[threadIdx.x] = s;
  __syncthreads();
  for (int w = 128; w > 0; w >>= 1) {
    if (threadIdx.x < w) red[threadIdx.x] += red[threadIdx.x + w];
    __syncthreads();
  }
  if (threadIdx.x == 0) sums[v] = red[0] + 1.0f;
}

__global__ void norm_k(const float* __restrict__ adj, const float* __restrict__ adjT,
                       const float* __restrict__ rs, const float* __restrict__ cs,
                       bf16* __restrict__ a1, bf16* __restrict__ a2) {
  int v = blockIdx.x & (N_NODES - 1);
  bool second = blockIdx.x >= N_NODES;
  const float* src = second ? adjT : adj;
  float inv = 1.0f / (second ? cs[v] : rs[v]);
  bf16* dst = second ? a2 : a1;
  for (int n = threadIdx.x; n < N_NODES; n += 256) {
    float val = src[(size_t)v * N_NODES + n] + (n == v ? 1.0f : 0.0f);
    dst[(size_t)v * N_NODES + n] = (bf16)(val * inv);
  }
}

// ---------------- bf16 1024x1024 transpose ----------------
__global__ __launch_bounds__(256) void btrans_k(const bf16* __restrict__ src,
                                                bf16* __restrict__ dst) {
  __shared__ __align__(16) bf16 t[64][72];
  int bx = blockIdx.x * 64, by = blockIdx.y * 64;
  int tid = threadIdx.x;
#pragma unroll
  for (int i = 0; i < 2; ++i) {
    int q = tid + i * 256;
    int r = q >> 3, c = (q & 7) * 8;
    *(uint4*)&t[r][c] = *(const uint4*)&src[(size_t)(by + r) * N_NODES + bx + c];
  }
  __syncthreads();
#pragma unroll
  for (int i = 0; i < 2; ++i) {
    int q = tid + i * 256;
    int rr = q >> 3, cc = (q & 7) * 8;
    bf16 tmp[8];
#pragma unroll
    for (int e = 0; e < 8; ++e) tmp[e] = t[cc + e][rr];
    *(uint4*)&dst[(size_t)(bx + rr) * N_NODES + by + cc] = *(uint4*)tmp;
  }
}

// ---------------- combined inception weights ----------------
__global__ void combine_w_k(const float* w0, const float* w1, const float* w2, const float* w3,
                            const float* w4, const float* w5, const float* b0, const float* b1,
                            const float* b2, const float* b3, const float* b4, const float* b5,
                            bf16* __restrict__ Wc, float* __restrict__ bsum) {
  int idx = blockIdx.x * 256 + threadIdx.x;
  if (idx < MAXK * 4096) {
    int dtI = idx >> 12;
    int dout = (idx >> 6) & 63;
    int di = idx & 63;
    int d = dtI - 5;
    int ad = d < 0 ? -d : d;
    const float* ws[6] = {w0, w1, w2, w3, w4, w5};
    float s = 0.f;
    for (int i = 0; i < 6; ++i)
      if (i >= ad) {
        int K = 2 * i + 1;
        s += ws[i][((size_t)dout * 64 + di) * K + (d + i)];
      }
    Wc[idx] = (bf16)s;
  }
  if (idx < 64) bsum[idx] = b0[idx] + b1[idx] + b2[idx] + b3[idx] + b4[idx] + b5[idx];
}

// Vt[5][dout][din]: folded mixprop matrices (A^2 trick); + gbsum
__global__ void vt_k(const float* __restrict__ g1w, const float* __restrict__ g2w,
                     const float* __restrict__ g1b, const float* __restrict__ g2b,
                     bf16* __restrict__ Vt, float* __restrict__ gbsum) {
  int idx = blockIdx.x * 256 + threadIdx.x;
  if (idx < 64) gbsum[idx] = g1b[idx] + g2b[idx];
  if (idx >= 5 * 4096) return;
  int j = idx >> 12;
  int dout = (idx >> 6) & 63;
  int din = idx & 63;
  const float al = 0.05f, bt = 0.95f;
  float v;
  if (j == 0)
    v = g1w[din * 64 + dout] + g2w[din * 64 + dout] +
        al * (g1w[(64 + din) * 64 + dout] + g1w[(128 + din) * 64 + dout] +
              g2w[(64 + din) * 64 + dout] + g2w[(128 + din) * 64 + dout]);
  else if (j == 1)
    v = bt * g1w[(64 + din) * 64 + dout] + al * bt * g1w[(128 + din) * 64 + dout];
  else if (j == 2)
    v = bt * bt * g1w[(128 + din) * 64 + dout];
  else if (j == 3)
    v = bt * g2w[(64 + din) * 64 + dout] + al * bt * g2w[(128 + din) * 64 + dout];
  else
    v = bt * bt * g2w[(128 + din) * 64 + dout];
  Vt[idx] = (bf16)v;
}

// w2T[dout][128]; dw1T[128][64]; dw2T[16][128] (rows 8..15 zero)
__global__ void prep_misc_k(const float* __restrict__ w2, const float* __restrict__ dw1,
                            const float* __restrict__ dw2, bf16* __restrict__ w2T,
                            bf16* __restrict__ dw1T, bf16* __restrict__ dw2T) {
  int i = blockIdx.x * 256 + threadIdx.x;
  if (i < 8192) {
    int dout = i >> 7, j = i & 127;
    w2T[i] = (bf16)w2[(size_t)j * 64 + dout];
    int jj = i >> 6, k = i & 63;
    dw1T[i] = (bf16)dw1[k * 128 + jj];
  }
  if (i < 2048) {
    int s = i >> 7, j = i & 127;
    dw2T[i] = (s < 8) ? (bf16)dw2[j * 8 + s] : (bf16)0.f;
  }
}

// ---------------- encoder ----------------
__global__ __launch_bounds__(256) void encoder_k(const float* __restrict__ x,
                                                 const float* __restrict__ w1,
                                                 const float* __restrict__ b1,
                                                 const bf16* __restrict__ w2T,
                                                 const float* __restrict__ b2,
                                                 bf16* __restrict__ resb) {
  __shared__ __align__(16) float xs[8 * 64];
  __shared__ __align__(16) float w1s[8 * 128];
  __shared__ float b1s[128];
  __shared__ float b2s[64];
  __shared__ __align__(16) bf16 hA[64 * 136];
  __shared__ __align__(16) bf16 wB[64 * 136];
  int tid = threadIdx.x;
  int v0 = blockIdx.x * 64;
  int bfp = blockIdx.y;
  int b = bfp / FREQ, f = bfp % FREQ;
#pragma unroll
  for (int i = 0; i < 2; ++i) {
    int q = tid + i * 256;
    xs[q] = x[(size_t)(b * 336 + f * 8 + (q >> 6)) * 1024 + v0 + (q & 63)];
  }
#pragma unroll
  for (int i = 0; i < 4; ++i) {
    int q = tid + i * 256;
    w1s[q] = w1[q];
  }
#pragma unroll
  for (int i = 0; i < 4; ++i) {
    int q = tid + i * 256;
    int dout = q >> 4, jc = (q & 15) * 8;
    *(uint4*)&wB[dout * 136 + jc] = *(const uint4*)&w2T[dout * 128 + jc];
  }
  if (tid < 128) b1s[tid] = b1[tid];
  if (tid < 64) b2s[tid] = b2[tid];
  __syncthreads();
  {
    int n = tid & 63, jc = (tid >> 6) * 32;
    for (int jj = 0; jj < 32; ++jj) {
      int j = jc + jj;
      float a = b1s[j];
#pragma unroll
      for (int k = 0; k < 8; ++k) a = fmaf(xs[k * 64 + n], w1s[k * 128 + j], a);
      hA[n * 136 + j] = (bf16)fmaxf(a, 0.f);
    }
  }
  __syncthreads();
  int wid = tid >> 6, lane = tid & 63, lr = lane & 15, lg = lane >> 4;
  f32x4 acc[4] = {};
#pragma unroll
  for (int ks = 0; ks < 4; ++ks) {
    bf16x8 a = *(const bf16x8*)&hA[(wid * 16 + lr) * 136 + ks * 32 + lg * 8];
#pragma unroll
    for (int ni = 0; ni < 4; ++ni) {
      bf16x8 bb = *(const bf16x8*)&wB[(ni * 16 + lr) * 136 + ks * 32 + lg * 8];
      acc[ni] = __builtin_amdgcn_mfma_f32_16x16x32_bf16(a, bb, acc[ni], 0, 0, 0);
    }
  }
  __syncthreads();
#pragma unroll
  for (int ni = 0; ni < 4; ++ni) {
    int n = ni * 16 + lr;
    float bz = b2s[n];
#pragma unroll
    for (int r = 0; r < 4; ++r) wB[(wid * 16 + lg * 4 + r) * 72 + n] = (bf16)(acc[ni][r] + bz);
  }
  __syncthreads();
  size_t so = (size_t)(b * FREQ + f) * SLICE;
#pragma unroll
  for (int i = 0; i < 2; ++i) {
    int q = tid + i * 256;
    int r = q >> 3, c = (q & 7) * 8;
    *(uint4*)&resb[so + (size_t)(v0 + r) * 64 + c] = *(uint4*)&wB[r * 72 + c];
  }
}

// ---------------- cur init ----------------
__global__ void curinit_k(const bf16* __restrict__ resb, float* __restrict__ cur,
                          bf16* __restrict__ curb) {
  size_t idx = (size_t)blockIdx.x * 256 + threadIdx.x;
  const size_t per_b = (size_t)MAXK * SLICE;
  if (idx < (size_t)NB * per_b) {
    size_t b = idx / per_b, rem = idx % per_b;
    bf16 v = resb[b * ((size_t)FREQ * SLICE) + (size_t)31 * SLICE + rem];
    cur[idx] = (float)v;
    curb[idx] = v;
  }
}

// ---------------- staging helpers ----------------
__device__ __forceinline__ void stageA(bf16* lds_a, const bf16* src, int rowStride, int tid) {
#pragma unroll
  for (int i = 0; i < 8; ++i) {
    int q = tid + i * 256;
    int r = q >> 3, c = (q & 7) << 3;
    *(uint4*)&lds_a[r * 72 + c] = *(const uint4*)&src[(size_t)r * rowStride + c];
  }
}
__device__ __forceinline__ void stageB(bf16* lds_b, const bf16* src, int rowStride, int tid) {
#pragma unroll
  for (int i = 0; i < 2; ++i) {
    int q = tid + i * 256;
    int r = q >> 3, c = (q & 7) << 3;
    *(uint4*)&lds_b[r * 72 + c] = *(const uint4*)&src[(size_t)r * rowStride + c];
  }
}
__device__ __forceinline__ void mfma64(const bf16* lds_a, const bf16* lds_b, int wid, int lane,
                                       f32x4 acc[4][4]) {
  int lr = lane & 15, lg = lane >> 4;
#pragma unroll
  for (int h = 0; h < 2; ++h) {
    bf16x8 af[4], bfr[4];
#pragma unroll
    for (int mi = 0; mi < 4; ++mi)
      af[mi] = *(const bf16x8*)&lds_a[(wid * 64 + mi * 16 + lr) * 72 + h * 32 + lg * 8];
#pragma unroll
    for (int ni = 0; ni < 4; ++ni)
      bfr[ni] = *(const bf16x8*)&lds_b[(ni * 16 + lr) * 72 + h * 32 + lg * 8];
#pragma unroll
    for (int mi = 0; mi < 4; ++mi)
#pragma unroll
      for (int ni = 0; ni < 4; ++ni)
        acc[mi][ni] =
            __builtin_amdgcn_mfma_f32_16x16x32_bf16(af[mi], bfr[ni], acc[mi][ni], 0, 0, 0);
  }
}

// ---------------- A^2 precompute ----------------
__global__ __launch_bounds__(256) void asq_k(const bf16* __restrict__ a,
                                             const bf16* __restrict__ aT,
                                             bf16* __restrict__ out) {
  __shared__ __align__(16) bf16 As[64 * 72];
  __shared__ __align__(16) bf16 Bs2[64 * 72];
  int tid = threadIdx.x, w = tid >> 6, lane = tid & 63;
  int lr = lane & 15, lg = lane >> 4;
  int v0 = blockIdx.x * 64, n0 = blockIdx.y * 64;
  f32x4 acc[4] = {};
  for (int k0 = 0; k0 < 1024; k0 += 64) {
    __syncthreads();
    stageB(As, a + (size_t)v0 * 1024 + k0, 1024, tid);
    stageB(Bs2, aT + (size_t)n0 * 1024 + k0, 1024, tid);
    __syncthreads();
#pragma unroll
    for (int h = 0; h < 2; ++h) {
      bf16x8 av = *(const bf16x8*)&As[(w * 16 + lr) * 72 + h * 32 + lg * 8];
#pragma unroll
      for (int ni = 0; ni < 4; ++ni) {
        bf16x8 bv = *(const bf16x8*)&Bs2[(ni * 16 + lr) * 72 + h * 32 + lg * 8];
        acc[ni] = __builtin_amdgcn_mfma_f32_16x16x32_bf16(av, bv, acc[ni], 0, 0, 0);
      }
    }
  }
#pragma unroll
  for (int ni = 0; ni < 4; ++ni)
#pragma unroll
    for (int r = 0; r < 4; ++r) As[(w * 16 + lg * 4 + r) * 72 + ni * 16 + lr] = (bf16)acc[ni][r];
  __syncthreads();
#pragma unroll
  for (int i = 0; i < 2; ++i) {
    int q = tid + i * 256;
    int r = q >> 3, c = (q & 7) * 8;
    *(uint4*)&out[(size_t)(v0 + r) * 1024 + n0 + c] = *(uint4*)&As[r * 72 + c];
  }
}

// ---------------- inception (rec): LDS-staged; grid (slices, 4 tiles) for XCD locality ----
__global__ __launch_bounds__(256) void incep_k(const bf16* __restrict__ resb, int b0,
                                               const bf16* __restrict__ Wc,
                                               const float* __restrict__ bsum,
                                               bf16* __restrict__ xcN, bf16* __restrict__ xcF) {
  __shared__ __align__(16) bf16 lds_a[256 * 72];
  __shared__ __align__(16) bf16 lds_b[64 * 72];
  int tid = threadIdx.x, wid = tid >> 6, lane = tid & 63;
  int v0 = blockIdx.y * 256;
  int sl = blockIdx.x;
  int b = b0 + sl / TREC, tt = sl % TREC;
  f32x4 acc[4][4] = {};
  for (int dt = 0; dt < MAXK; ++dt) {
    int ts = tt + dt - 5;
    if (ts < 0 || ts >= TREC) continue;
    __syncthreads();
    stageA(lds_a, resb + (size_t)(b * FREQ + ts) * SLICE + (size_t)v0 * 64, 64, tid);
    stageB(lds_b, Wc + dt * 4096, 64, tid);
    __syncthreads();
    mfma64(lds_a, lds_b, wid, lane, acc);
  }
  int lr = lane & 15, lg = lane >> 4;
  size_t so = (size_t)sl * SLICE;
  __syncthreads();
#pragma unroll
  for (int mi = 0; mi < 4; ++mi)
#pragma unroll
    for (int ni = 0; ni < 4; ++ni) {
      int n = ni * 16 + lr;
      float bs = bsum[n];
      union { bf16 h[4]; uint2 u; } pk;
#pragma unroll
      for (int r = 0; r < 4; ++r) {
        int m = wid * 64 + mi * 16 + lg * 4 + r;
        bf16 bv = (bf16)((acc[mi][ni][r] + bs) * (1.f / 6.f));
        lds_a[m * 72 + n] = bv;
        pk.h[r] = bv;
      }
      *(uint2*)&xcF[so + (size_t)n * 1024 + v0 + wid * 64 + mi * 16 + lg * 4] = pk.u;
    }
  __syncthreads();
#pragma unroll
  for (int i = 0; i < 8; ++i) {
    int q = tid + i * 256;
    int r = q >> 3, c = (q & 7) * 8;
    *(uint4*)&xcN[so + (size_t)(v0 + r) * 64 + c] = *(uint4*)&lds_a[r * 72 + c];
  }
}

// ---------------- fused rec: grid (slices, 16 tiles) so one slice = one XCD ----------------
__global__ __launch_bounds__(256) void fusedrec_k(
    const bf16* __restrict__ xcN, const bf16* __restrict__ xcF, const bf16* __restrict__ a1,
    const bf16* __restrict__ a1q, const bf16* __restrict__ a2, const bf16* __restrict__ a2q,
    const bf16* __restrict__ Vt, const float* __restrict__ gbsum,
    const bf16* __restrict__ resb, int b0, const bf16* __restrict__ dw1T,
    const float* __restrict__ db1, const bf16* __restrict__ dw2T,
    const float* __restrict__ db2, float* __restrict__ outRec) {
  __shared__ __align__(16) bf16 regA[4][64 * 72];  // A panels -> P panels -> hb
  __shared__ __align__(16) bf16 regB[64 * 72];     // xcF chunk -> xcN tile -> valb
  bf16* hb = &regA[0][0];
  bf16* valb = &regB[0];
  int tid = threadIdx.x, w = tid >> 6, lane = tid & 63;
  int lr = lane & 15, lg = lane >> 4;
  int v0 = blockIdx.y * 64;
  int sy = blockIdx.x;
  int bl = sy / FREQ, f = sy % FREQ;
  int b = b0 + bl;

  if (f == 0) {
    const bf16* src = resb + (size_t)(b * FREQ) * SLICE + (size_t)v0 * 64;
#pragma unroll
    for (int i = 0; i < 2; ++i) {
      int q = tid + i * 256;
      int r = q >> 3, c = (q & 7) * 8;
      *(uint4*)&valb[r * 72 + c] = *(const uint4*)&src[(size_t)r * 64 + c];
    }
    __syncthreads();
  } else {
    int tt = f - 1;
    size_t so = (size_t)(bl * TREC + tt) * SLICE;
    f32x4 acc[4][4] = {};
    for (int k0 = 0; k0 < 1024; k0 += 64) {
      __syncthreads();
#pragma unroll
      for (int i = 0; i < 8; ++i) {
        int q = tid + i * 256;
        int mm = q >> 9, pos = q & 511;
        int rr = pos >> 3, cc = (pos & 7) * 8;
        const bf16* mp = mm == 0 ? a1 : (mm == 1 ? a1q : (mm == 2 ? a2 : a2q));
        *(uint4*)&regA[mm][rr * 72 + cc] =
            *(const uint4*)&mp[(size_t)(v0 + rr) * 1024 + k0 + cc];
      }
#pragma unroll
      for (int i = 0; i < 2; ++i) {
        int q = tid + i * 256;
        int rb = q >> 3, cbb = (q & 7) * 8;
        *(uint4*)&regB[rb * 72 + cbb] = *(const uint4*)&xcF[so + (size_t)rb * 1024 + k0 + cbb];
      }
      __syncthreads();
#pragma unroll
      for (int h = 0; h < 2; ++h) {
        bf16x8 af[4], bfr[4];
#pragma unroll
        for (int mi = 0; mi < 4; ++mi)
          af[mi] = *(const bf16x8*)&regA[w][(mi * 16 + lr) * 72 + h * 32 + lg * 8];
#pragma unroll
        for (int ni = 0; ni < 4; ++ni)
          bfr[ni] = *(const bf16x8*)&regB[(ni * 16 + lr) * 72 + h * 32 + lg * 8];
#pragma unroll
        for (int mi = 0; mi < 4; ++mi)
#pragma unroll
          for (int ni = 0; ni < 4; ++ni)
            acc[mi][ni] =
                __builtin_amdgcn_mfma_f32_16x16x32_bf16(af[mi], bfr[ni], acc[mi][ni], 0, 0, 0);
      }
    }
    __syncthreads();  // all waves done with regA panels + regB chunk
    // P -> regA[w]; xcN tile -> regB
#pragma unroll
    for (int mi = 0; mi < 4; ++mi)
#pragma unroll
      for (int ni = 0; ni < 4; ++ni)
#pragma unroll
        for (int r = 0; r < 4; ++r)
          regA[w][(mi * 16 + lg * 4 + r) * 72 + ni * 16 + lr] = (bf16)acc[mi][ni][r];
#pragma unroll
    for (int i = 0; i < 2; ++i) {
      int q = tid + i * 256;
      int r = q >> 3, c = (q & 7) * 8;
      *(uint4*)&regB[r * 72 + c] = *(const uint4*)&xcN[so + (size_t)(v0 + r) * 64 + c];
    }
    __syncthreads();
    // combine: wave w -> rows w*16..w*16+15 ; result kept in registers
    f32x4 z[4] = {};
#pragma unroll
    for (int j = 0; j < 5; ++j) {
      const bf16* Asrc = (j == 0) ? regB : &regA[j - 1][0];
#pragma unroll
      for (int h = 0; h < 2; ++h) {
        bf16x8 a = *(const bf16x8*)&Asrc[(w * 16 + lr) * 72 + h * 32 + lg * 8];
#pragma unroll
        for (int ni = 0; ni < 4; ++ni) {
          bf16x8 bb =
              *(const bf16x8*)&Vt[(size_t)j * 4096 + (ni * 16 + lr) * 64 + h * 32 + lg * 8];
          z[ni] = __builtin_amdgcn_mfma_f32_16x16x32_bf16(a, bb, z[ni], 0, 0, 0);
        }
      }
    }
    const bf16* xb = resb + (size_t)(b * FREQ + tt) * SLICE + (size_t)v0 * 64;
    float vals[4][4];
#pragma unroll
    for (int ni = 0; ni < 4; ++ni) {
      int n = ni * 16 + lr;
      float gb = gbsum[n];
#pragma unroll
      for (int r = 0; r < 4; ++r) {
        int m = w * 16 + lg * 4 + r;
        vals[ni][r] = (float)xb[(size_t)m * 64 + n] + z[ni][r] + gb;
      }
    }
    __syncthreads();  // all waves done reading regB (j=0 operand)
#pragma unroll
    for (int ni = 0; ni < 4; ++ni) {
      int n = ni * 16 + lr;
#pragma unroll
      for (int r = 0; r < 4; ++r)
        valb[(w * 16 + lg * 4 + r) * 72 + n] = (bf16)vals[ni][r];
    }
    __syncthreads();
  }
  // ---- decoder layer1 (64->128 relu): wave w -> cols w*32..w*32+31 ----
  f32x4 hacc[4][2] = {};
#pragma unroll
  for (int h = 0; h < 2; ++h) {
    bf16x8 a[4];
#pragma unroll
    for (int mi = 0; mi < 4; ++mi)
      a[mi] = *(const bf16x8*)&valb[(mi * 16 + lr) * 72 + h * 32 + lg * 8];
#pragma unroll
    for (int ni2 = 0; ni2 < 2; ++ni2) {
      bf16x8 bb = *(const bf16x8*)&dw1T[(w * 32 + ni2 * 16 + lr) * 64 + h * 32 + lg * 8];
#pragma unroll
      for (int mi = 0; mi < 4; ++mi)
        hacc[mi][ni2] = __builtin_amdgcn_mfma_f32_16x16x32_bf16(a[mi], bb, hacc[mi][ni2], 0, 0, 0);
    }
  }
  __syncthreads();  // regA (P panels) fully consumed; reuse as hb
#pragma unroll
  for (int ni2 = 0; ni2 < 2; ++ni2) {
    int j = w * 32 + ni2 * 16 + lr;
    float bz = db1[j];
#pragma unroll
    for (int mi = 0; mi < 4; ++mi)
#pragma unroll
      for (int r = 0; r < 4; ++r)
        hb[(mi * 16 + lg * 4 + r) * 136 + j] = (bf16)fmaxf(hacc[mi][ni2][r] + bz, 0.f);
  }
  __syncthreads();
  // ---- layer2 (128->8) ----
  f32x4 oacc = {};
#pragma unroll
  for (int kc = 0; kc < 4; ++kc) {
    bf16x8 a = *(const bf16x8*)&hb[(w * 16 + lr) * 136 + kc * 32 + lg * 8];
    bf16x8 bb = *(const bf16x8*)&dw2T[lr * 128 + kc * 32 + lg * 8];
    oacc = __builtin_amdgcn_mfma_f32_16x16x32_bf16(a, bb, oacc, 0, 0, 0);
  }
  if (lr < 8) {
    float bz = db2[lr];
    float4 o;
    o.x = oacc[0] + bz;
    o.y = oacc[1] + bz;
    o.z = oacc[2] + bz;
    o.w = oacc[3] + bz;
    *(float4*)&outRec[(size_t)b * 344064 + (size_t)(f * 8 + lr) * 1024 + v0 + w * 16 + lg * 4] =
        o;
  }
}

// ---------------- AR branch v6: group-per-XCD mapping ----------------
__device__ __forceinline__ void arrive_wait(unsigned* c, int tid) {
  __syncthreads();
  if (tid == 0) {
    __hip_atomic_fetch_add(c, 1u, __ATOMIC_RELAXED, __HIP_MEMORY_SCOPE_AGENT);
    while (__hip_atomic_load(c, __ATOMIC_RELAXED, __HIP_MEMORY_SCOPE_AGENT) < 64u)
      __builtin_amdgcn_s_sleep(8);
  }
  __syncthreads();
}

__device__ __forceinline__ void incep16(const bf16* __restrict__ curb,
                                        const bf16* __restrict__ Wc, const float* bsums_,
                                        int base, int b, int r0, int w, int lr, int lg,
                                        bf16* yL, bf16* yFdst) {
  f32x4 ya = {};
  for (int j = 0; j < 6; ++j) {
    int slot = (base + 5 + j) % MAXK;
    const bf16* cb = curb + ((size_t)b * MAXK + slot) * SLICE + (size_t)r0 * 64;
#pragma unroll
    for (int h = 0; h < 2; ++h) {
      bf16x8 a = *(const bf16x8*)&cb[lr * 64 + h * 32 + lg * 8];
      bf16x8 bb = *(const bf16x8*)&Wc[(size_t)j * 4096 + (w * 16 + lr) * 64 + h * 32 + lg * 8];
      ya = __builtin_amdgcn_mfma_f32_16x16x32_bf16(a, bb, ya, 0, 0, 0);
    }
  }
  int n = w * 16 + lr;
  float bs = bsums_[n];
  union { bf16 h[4]; unsigned long long u; } pk;
#pragma unroll
  for (int r = 0; r < 4; ++r) {
    int m = lg * 4 + r;
    bf16 bv = (bf16)((ya[r] + bs) * (1.f / 6.f));
    yL[m * 72 + n] = bv;
    pk.h[r] = bv;
  }
  __hip_atomic_store((unsigned long long*)(yFdst + (size_t)n * 1024 + r0 + lg * 4), pk.u,
                     __ATOMIC_RELAXED, __HIP_MEMORY_SCOPE_AGENT);
}

struct AR5 {
  const bf16 *Wc;
  const float *bsum;
  const bf16 *a1, *a1q, *a2, *a2q;
  const bf16 *Vt;
  const float *gbsum;
  float *cur;
  bf16 *curb;
  bf16 *yF;
  const bf16 *dw1T;
  const float *db1;
  const bf16 *dw2T;
  const float *db2;
  float *outPred;
  unsigned *bar;
};

__global__ void __launch_bounds__(256) ar6_k(AR5 p) {
  __shared__ __align__(16) bf16 As4[2][4][16 * 72];
  __shared__ __align__(16) bf16 Bs[2][64 * 72];
  __shared__ __align__(16) bf16 yL[16 * 72];
  __shared__ __align__(16) bf16 PL[4][16 * 72];
  __shared__ __align__(16) bf16 valb[16 * 72];
  __shared__ __align__(16) bf16 hb[16 * 136];
  __shared__ float db1s[128], db2s[8], bsums[64], gbsums[64];
  int tid = threadIdx.x, w = tid >> 6, lane = tid & 63;
  int lr = lane & 15, lg = lane >> 4;
  int bid = blockIdx.x;
  int b = bid & 7, l = bid >> 3;  // group b's 64 blocks land on one XCD (id % 8)
  unsigned* cnt = p.bar + b * 32;
  int r0 = l * 16;

  if (tid < 128) db1s[tid] = p.db1[tid];
  if (tid < 8) db2s[tid] = p.db2[tid];
  if (tid < 64) {
    bsums[tid] = p.bsum[tid];
    gbsums[tid] = p.gbsum[tid];
  }
  __syncthreads();

  incep16(p.curb, p.Wc, bsums, 0, b, r0, w, lr, lg, yL, p.yF + (size_t)b * SLICE);
  arrive_wait(cnt + 0, tid);

  const bf16* mats[4] = {p.a1, p.a1q, p.a2, p.a2q};
  for (int s = 0; s < NSTEP; ++s) {
    {
      const bf16* yFs = p.yF + ((size_t)s * NB + b) * SLICE;
      f32x4 acc[4] = {};
      auto stage_chunk = [&](int d, int k0) {
#pragma unroll
        for (int i = 0; i < 2; ++i) {
          int q = tid + i * 256;
          int mm = q >> 7, rr = (q >> 3) & 15, cc = (q & 7) * 8;
          *(uint4*)&As4[d][mm][rr * 72 + cc] =
              *(const uint4*)&mats[mm][(size_t)(r0 + rr) * 1024 + k0 + cc];
          int rb = q >> 3, cb2 = (q & 7) * 8;
          *(uint4*)&Bs[d][rb * 72 + cb2] = *(const uint4*)&yFs[(size_t)rb * 1024 + k0 + cb2];
        }
      };
      stage_chunk(0, 0);
      for (int c = 0; c < 16; ++c) {
        __syncthreads();
        if (c < 15) stage_chunk((c + 1) & 1, (c + 1) * 64);
#pragma unroll
        for (int h = 0; h < 2; ++h) {
          bf16x8 a = *(const bf16x8*)&As4[c & 1][w][lr * 72 + h * 32 + lg * 8];
#pragma unroll
          for (int ni = 0; ni < 4; ++ni) {
            bf16x8 bb = *(const bf16x8*)&Bs[c & 1][(ni * 16 + lr) * 72 + h * 32 + lg * 8];
            acc[ni] = __builtin_amdgcn_mfma_f32_16x16x32_bf16(a, bb, acc[ni], 0, 0, 0);
          }
        }
      }
#pragma unroll
      for (int ni = 0; ni < 4; ++ni) {
        int nn = ni * 16 + lr;
#pragma unroll
        for (int r = 0; r < 4; ++r) PL[w][(lg * 4 + r) * 72 + nn] = (bf16)acc[ni][r];
      }
    }
    __syncthreads();
    {
      f32x4 z = {};
#pragma unroll
      for (int j = 0; j < 5; ++j) {
        const bf16* Aj = (j == 0) ? yL : PL[j - 1];
#pragma unroll
        for (int h = 0; h < 2; ++h) {
          bf16x8 a = *(const bf16x8*)&Aj[lr * 72 + h * 32 + lg * 8];
          bf16x8 bb =
              *(const bf16x8*)&p.Vt[(size_t)j * 4096 + (w * 16 + lr) * 64 + h * 32 + lg * 8];
          z = __builtin_amdgcn_mfma_f32_16x16x32_bf16(a, bb, z, 0, 0, 0);
        }
      }
      int slotR = (s + 10) % MAXK, slotW = s % MAXK;
      size_t xo = ((size_t)b * MAXK + slotR) * SLICE + (size_t)r0 * 64;
      size_t wo = ((size_t)b * MAXK + slotW) * SLICE + (size_t)r0 * 64;
      int n = w * 16 + lr;
      float gb = gbsums[n];
#pragma unroll
      for (int r = 0; r < 4; ++r) {
        int m = lg * 4 + r;
        size_t o = (size_t)m * 64 + n;
        float v = p.cur[xo + o] + z[r] + gb;
        p.cur[wo + o] = v;
        p.curb[wo + o] = (bf16)v;
        valb[m * 72 + n] = (bf16)v;
      }
      __syncthreads();
      if (s < NSTEP - 1)
        incep16(p.curb, p.Wc, bsums, s + 1, b, r0, w, lr, lg, yL,
                p.yF + ((size_t)(s + 1) * NB + b) * SLICE);
      f32x4 hacc[2] = {};
#pragma unroll
      for (int h = 0; h < 2; ++h) {
        bf16x8 a = *(const bf16x8*)&valb[lr * 72 + h * 32 + lg * 8];
#pragma unroll
        for (int ni2 = 0; ni2 < 2; ++ni2) {
          bf16x8 bb = *(const bf16x8*)&p.dw1T[(w * 32 + ni2 * 16 + lr) * 64 + h * 32 + lg * 8];
          hacc[ni2] = __builtin_amdgcn_mfma_f32_16x16x32_bf16(a, bb, hacc[ni2], 0, 0, 0);
        }
      }
#pragma unroll
      for (int ni2 = 0; ni2 < 2; ++ni2) {
        int j = w * 32 + ni2 * 16 + lr;
        float bz = db1s[j];
#pragma unroll
        for (int r = 0; r < 4; ++r)
          hb[(lg * 4 + r) * 136 + j] = (bf16)fmaxf(hacc[ni2][r] + bz, 0.f);
      }
      __syncthreads();
      f32x4 oacc = {};
#pragma unroll
      for (int kc = 0; kc < 4; ++kc) {
        bf16x8 a = *(const bf16x8*)&hb[lr * 136 + kc * 32 + lg * 8];
        bf16x8 bb = *(const bf16x8*)&p.dw2T[lr * 128 + kc * 32 + lg * 8];
        oacc = __builtin_amdgcn_mfma_f32_16x16x32_bf16(a, bb, oacc, 0, 0, 0);
      }
      if (w == 0 && lr < 8) {
        float bz = db2s[lr];
#pragma unroll
        for (int r = 0; r < 4; ++r)
          p.outPred[(size_t)b * 98304 + (size_t)s * 8192 + (size_t)(r0 + lg * 4 + r) * 8 + lr] =
              oacc[r] + bz;
      }
    }
    if (s < NSTEP - 1) arrive_wait(cnt + 1 + s, tid);
  }
}

// ---------------- host launch ----------------
extern "C" void kernel_launch(void* const* d_in, const int* in_sizes, int n_in, void* d_out,
                              int out_size, void* d_ws, size_t ws_size, hipStream_t stream) {
  const float* x_diff = (const float*)d_in[0];
  const float* adj = (const float*)d_in[1];
  const float* enc_w1 = (const float*)d_in[2];
  const float* enc_b1 = (const float*)d_in[3];
  const float* enc_w2 = (const float*)d_in[4];
  const float* enc_b2 = (const float*)d_in[5];
  const float* dec_w1 = (const float*)d_in[6];
  const float* dec_b1 = (const float*)d_in[7];
  const float* dec_w2 = (const float*)d_in[8];
  const float* dec_b2 = (const float*)d_in[9];
  const float* g1_w = (const float*)d_in[10];
  const float* g1_b = (const float*)d_in[11];
  const float* g2_w = (const float*)d_in[12];
  const float* g2_b = (const float*)d_in[13];
  const float* cw[6];
  const float* cb_[6];
  for (int i = 0; i < 6; ++i) {
    cw[i] = (const float*)d_in[14 + 2 * i];
    cb_[i] = (const float*)d_in[15 + 2 * i];
  }

  char* base = (char*)d_ws;
  size_t off = 0;
  auto alloc = [&](size_t bytes) -> void* {
    void* p = base + off;
    off = (off + bytes + 255) & ~(size_t)255;
    return p;
  };
  float* adjT = (float*)alloc(1048576ULL * 4);
  float* rowsum = (float*)alloc(4096);
  float* colsum = (float*)alloc(4096);
  bf16* a1b = (bf16*)alloc(1048576ULL * 2);
  bf16* a2b = (bf16*)alloc(1048576ULL * 2);
  bf16* a1T = (bf16*)alloc(1048576ULL * 2);
  bf16* a2T = (bf16*)alloc(1048576ULL * 2);
  bf16* a1q = (bf16*)alloc(1048576ULL * 2);
  bf16* a2q = (bf16*)alloc(1048576ULL * 2);
  bf16* Wc = (bf16*)alloc(45056ULL * 2);
  float* bsum = (float*)alloc(256);
  float* gbsum = (float*)alloc(256);
  bf16* Vt = (bf16*)alloc(20480ULL * 2);
  bf16* w2T = (bf16*)alloc(8192ULL * 2);
  bf16* dw1T = (bf16*)alloc(8192ULL * 2);
  bf16* dw2T = (bf16*)alloc(2048ULL * 2);
  bf16* resb = (bf16*)alloc((size_t)NB * FREQ * SLICE * 2);
  float* cur = (float*)alloc((size_t)NB * MAXK * SLICE * 4);
  bf16* curb = (bf16*)alloc((size_t)NB * MAXK * SLICE * 2);
  bf16* yF = (bf16*)alloc((size_t)NSTEP * NB * SLICE * 2);
  unsigned* gbar = (unsigned*)alloc(4096);
  size_t fixedEnd = off;
  int cb = NB;
  while (cb > 1) {
    size_t S = (size_t)TREC * cb;
    if (fixedEnd + S * SLICE * 4 + 65536 <= ws_size) break;
    cb >>= 1;
  }
  size_t S = (size_t)TREC * cb;
  bf16* xcN = (bf16*)alloc(S * SLICE * 2);
  bf16* xcF = (bf16*)alloc(S * SLICE * 2);

  float* outF = (float*)d_out;
  float* outRec = outF;
  float* outPred = outF + (size_t)2752512;

  transpose_k<<<dim3(32, 32), dim3(32, 8), 0, stream>>>(adj, adjT);
  rowsum_k<<<1024, 256, 0, stream>>>(adj, rowsum);
  rowsum_k<<<1024, 256, 0, stream>>>(adjT, colsum);
  norm_k<<<2048, 256, 0, stream>>>(adj, adjT, rowsum, colsum, a1b, a2b);
  btrans_k<<<dim3(16, 16), 256, 0, stream>>>(a1b, a1T);
  btrans_k<<<dim3(16, 16), 256, 0, stream>>>(a2b, a2T);
  asq_k<<<dim3(16, 16), 256, 0, stream>>>(a1b, a1T, a1q);
  asq_k<<<dim3(16, 16), 256, 0, stream>>>(a2b, a2T, a2q);
  combine_w_k<<<(MAXK * 4096 + 255) / 256, 256, 0, stream>>>(cw[0], cw[1], cw[2], cw[3], cw[4],
                                                             cw[5], cb_[0], cb_[1], cb_[2],
                                                             cb_[3], cb_[4], cb_[5], Wc, bsum);
  vt_k<<<80, 256, 0, stream>>>(g1_w, g2_w, g1_b, g2_b, Vt, gbsum);
  prep_misc_k<<<32, 256, 0, stream>>>(enc_w2, dec_w1, dec_w2, w2T, dw1T, dw2T);
  encoder_k<<<dim3(16, NB * FREQ), 256, 0, stream>>>(x_diff, enc_w1, enc_b1, w2T, enc_b2,
                                                     resb);
  curinit_k<<<(int)(((size_t)NB * MAXK * SLICE + 255) / 256), 256, 0, stream>>>(resb, cur,
                                                                                curb);

  // ---- reconstruction branch (XCD-local grids) ----
  for (int c0 = 0; c0 < NB; c0 += cb) {
    int Sg = TREC * cb;
    incep_k<<<dim3(Sg, 4), 256, 0, stream>>>(resb, c0, Wc, bsum, xcN, xcF);
    fusedrec_k<<<dim3(cb * FREQ, 16), 256, 0, stream>>>(xcN, xcF, a1b, a1q, a2b, a2q, Vt,
                                                        gbsum, resb, c0, dw1T, dec_b1, dw2T,
                                                        dec_b2, outRec);
  }

  // ---- autoregressive branch ----
  hipMemsetAsync(gbar, 0, 4096, stream);
  AR5 arp;
  arp.Wc = Wc; arp.bsum = bsum;
  arp.a1 = a1b; arp.a1q = a1q; arp.a2 = a2b; arp.a2q = a2q;
  arp.Vt = Vt; arp.gbsum = gbsum;
  arp.cur = cur; arp.curb = curb;
  arp.yF = yF;
  arp.dw1T = dw1T; arp.db1 = dec_b1; arp.dw2T = dw2T; arp.db2 = dec_b2;
  arp.outPred = outPred;
  arp.bar = gbar;
  ar6_k<<<dim3(512), dim3(256), 0, stream>>>(arp);
}

// Round 14
// 816.533 us; speedup vs baseline: 1.1087x; 1.1087x over previous
//
#include <hip/hip_runtime.h>

typedef __bf16 bf16;
typedef __bf16 bf16x8 __attribute__((ext_vector_type(8)));
typedef float f32x4 __attribute__((ext_vector_type(4)));

#define N_NODES 1024
#define DC 64
#define FREQ 42
#define TREC 41
#define NB 8
#define MAXK 11
#define NSTEP 12
#define SLICE 65536

// ---------------- adjacency prep ----------------
__global__ void transpose_k(const float* __restrict__ in, float* __restrict__ out) {
  __shared__ float tile[32][33];
  int bx = blockIdx.x * 32, by = blockIdx.y * 32;
  int x = threadIdx.x, y = threadIdx.y;
#pragma unroll
  for (int j = 0; j < 32; j += 8) tile[y + j][x] = in[(size_t)(by + y + j) * N_NODES + bx + x];
  __syncthreads();
#pragma unroll
  for (int j = 0; j < 32; j += 8) out[(size_t)(bx + y + j) * N_NODES + by + x] = tile[x][y + j];
}

__global__ void rowsum_k(const float* __restrict__ m, float* __restrict__ sums) {
  int v = blockIdx.x;
  float s = 0.f;
  for (int n = threadIdx.x; n < N_NODES; n += 256) s += m[(size_t)v * N_NODES + n];
  __shared__ float red[256];
  red[threadIdx.x] = s;
  __syncthreads();
  for (int w = 128; w > 0; w >>= 1) {
    if (threadIdx.x < w) red[threadIdx.x] += red[threadIdx.x + w];
    __syncthreads();
  }
  if (threadIdx.x == 0) sums[v] = red[0] + 1.0f;
}

__global__ void norm_k(const float* __restrict__ adj, const float* __restrict__ adjT,
                       const float* __restrict__ rs, const float* __restrict__ cs,
                       bf16* __restrict__ a1, bf16* __restrict__ a2) {
  int v = blockIdx.x & (N_NODES - 1);
  bool second = blockIdx.x >= N_NODES;
  const float* src = second ? adjT : adj;
  float inv = 1.0f / (second ? cs[v] : rs[v]);
  bf16* dst = second ? a2 : a1;
  for (int n = threadIdx.x; n < N_NODES; n += 256) {
    float val = src[(size_t)v * N_NODES + n] + (n == v ? 1.0f : 0.0f);
    dst[(size_t)v * N_NODES + n] = (bf16)(val * inv);
  }
}

// ---------------- bf16 1024x1024 transpose ----------------
__global__ __launch_bounds__(256) void btrans_k(const bf16* __restrict__ src,
                                                bf16* __restrict__ dst) {
  __shared__ __align__(16) bf16 t[64][72];
  int bx = blockIdx.x * 64, by = blockIdx.y * 64;
  int tid = threadIdx.x;
#pragma unroll
  for (int i = 0; i < 2; ++i) {
    int q = tid + i * 256;
    int r = q >> 3, c = (q & 7) * 8;
    *(uint4*)&t[r][c] = *(const uint4*)&src[(size_t)(by + r) * N_NODES + bx + c];
  }
  __syncthreads();
#pragma unroll
  for (int i = 0; i < 2; ++i) {
    int q = tid + i * 256;
    int rr = q >> 3, cc = (q & 7) * 8;
    bf16 tmp[8];
#pragma unroll
    for (int e = 0; e < 8; ++e) tmp[e] = t[cc + e][rr];
    *(uint4*)&dst[(size_t)(bx + rr) * N_NODES + by + cc] = *(uint4*)tmp;
  }
}

// ---------------- combined inception weights ----------------
__global__ void combine_w_k(const float* w0, const float* w1, const float* w2, const float* w3,
                            const float* w4, const float* w5, const float* b0, const float* b1,
                            const float* b2, const float* b3, const float* b4, const float* b5,
                            bf16* __restrict__ Wc, float* __restrict__ bsum) {
  int idx = blockIdx.x * 256 + threadIdx.x;
  if (idx < MAXK * 4096) {
    int dtI = idx >> 12;
    int dout = (idx >> 6) & 63;
    int di = idx & 63;
    int d = dtI - 5;
    int ad = d < 0 ? -d : d;
    const float* ws[6] = {w0, w1, w2, w3, w4, w5};
    float s = 0.f;
    for (int i = 0; i < 6; ++i)
      if (i >= ad) {
        int K = 2 * i + 1;
        s += ws[i][((size_t)dout * 64 + di) * K + (d + i)];
      }
    Wc[idx] = (bf16)s;
  }
  if (idx < 64) bsum[idx] = b0[idx] + b1[idx] + b2[idx] + b3[idx] + b4[idx] + b5[idx];
}

// Vt[5][dout][din]: folded mixprop matrices (A^2 trick); + gbsum
__global__ void vt_k(const float* __restrict__ g1w, const float* __restrict__ g2w,
                     const float* __restrict__ g1b, const float* __restrict__ g2b,
                     bf16* __restrict__ Vt, float* __restrict__ gbsum) {
  int idx = blockIdx.x * 256 + threadIdx.x;
  if (idx < 64) gbsum[idx] = g1b[idx] + g2b[idx];
  if (idx >= 5 * 4096) return;
  int j = idx >> 12;
  int dout = (idx >> 6) & 63;
  int din = idx & 63;
  const float al = 0.05f, bt = 0.95f;
  float v;
  if (j == 0)
    v = g1w[din * 64 + dout] + g2w[din * 64 + dout] +
        al * (g1w[(64 + din) * 64 + dout] + g1w[(128 + din) * 64 + dout] +
              g2w[(64 + din) * 64 + dout] + g2w[(128 + din) * 64 + dout]);
  else if (j == 1)
    v = bt * g1w[(64 + din) * 64 + dout] + al * bt * g1w[(128 + din) * 64 + dout];
  else if (j == 2)
    v = bt * bt * g1w[(128 + din) * 64 + dout];
  else if (j == 3)
    v = bt * g2w[(64 + din) * 64 + dout] + al * bt * g2w[(128 + din) * 64 + dout];
  else
    v = bt * bt * g2w[(128 + din) * 64 + dout];
  Vt[idx] = (bf16)v;
}

// w2T[dout][128]; dw1T[128][64]; dw2T[16][128] (rows 8..15 zero)
__global__ void prep_misc_k(const float* __restrict__ w2, const float* __restrict__ dw1,
                            const float* __restrict__ dw2, bf16* __restrict__ w2T,
                            bf16* __restrict__ dw1T, bf16* __restrict__ dw2T) {
  int i = blockIdx.x * 256 + threadIdx.x;
  if (i < 8192) {
    int dout = i >> 7, j = i & 127;
    w2T[i] = (bf16)w2[(size_t)j * 64 + dout];
    int jj = i >> 6, k = i & 63;
    dw1T[i] = (bf16)dw1[k * 128 + jj];
  }
  if (i < 2048) {
    int s = i >> 7, j = i & 127;
    dw2T[i] = (s < 8) ? (bf16)dw2[j * 8 + s] : (bf16)0.f;
  }
}

// ---------------- encoder (+ fused cur-ring init for f in [31,41]) ----------------
__global__ __launch_bounds__(256) void encoder_k(const float* __restrict__ x,
                                                 const float* __restrict__ w1,
                                                 const float* __restrict__ b1,
                                                 const bf16* __restrict__ w2T,
                                                 const float* __restrict__ b2,
                                                 bf16* __restrict__ resb,
                                                 float* __restrict__ cur,
                                                 bf16* __restrict__ curb) {
  __shared__ __align__(16) float xs[8 * 64];
  __shared__ __align__(16) float w1s[8 * 128];
  __shared__ float b1s[128];
  __shared__ float b2s[64];
  __shared__ __align__(16) bf16 hA[64 * 136];
  __shared__ __align__(16) bf16 wB[64 * 136];
  int tid = threadIdx.x;
  int v0 = blockIdx.x * 64;
  int bfp = blockIdx.y;
  int b = bfp / FREQ, f = bfp % FREQ;
#pragma unroll
  for (int i = 0; i < 2; ++i) {
    int q = tid + i * 256;
    xs[q] = x[(size_t)(b * 336 + f * 8 + (q >> 6)) * 1024 + v0 + (q & 63)];
  }
#pragma unroll
  for (int i = 0; i < 4; ++i) {
    int q = tid + i * 256;
    w1s[q] = w1[q];
  }
#pragma unroll
  for (int i = 0; i < 4; ++i) {
    int q = tid + i * 256;
    int dout = q >> 4, jc = (q & 15) * 8;
    *(uint4*)&wB[dout * 136 + jc] = *(const uint4*)&w2T[dout * 128 + jc];
  }
  if (tid < 128) b1s[tid] = b1[tid];
  if (tid < 64) b2s[tid] = b2[tid];
  __syncthreads();
  {
    int n = tid & 63, jc = (tid >> 6) * 32;
    for (int jj = 0; jj < 32; ++jj) {
      int j = jc + jj;
      float a = b1s[j];
#pragma unroll
      for (int k = 0; k < 8; ++k) a = fmaf(xs[k * 64 + n], w1s[k * 128 + j], a);
      hA[n * 136 + j] = (bf16)fmaxf(a, 0.f);
    }
  }
  __syncthreads();
  int wid = tid >> 6, lane = tid & 63, lr = lane & 15, lg = lane >> 4;
  f32x4 acc[4] = {};
#pragma unroll
  for (int ks = 0; ks < 4; ++ks) {
    bf16x8 a = *(const bf16x8*)&hA[(wid * 16 + lr) * 136 + ks * 32 + lg * 8];
#pragma unroll
    for (int ni = 0; ni < 4; ++ni) {
      bf16x8 bb = *(const bf16x8*)&wB[(ni * 16 + lr) * 136 + ks * 32 + lg * 8];
      acc[ni] = __builtin_amdgcn_mfma_f32_16x16x32_bf16(a, bb, acc[ni], 0, 0, 0);
    }
  }
  __syncthreads();
#pragma unroll
  for (int ni = 0; ni < 4; ++ni) {
    int n = ni * 16 + lr;
    float bz = b2s[n];
#pragma unroll
    for (int r = 0; r < 4; ++r) wB[(wid * 16 + lg * 4 + r) * 72 + n] = (bf16)(acc[ni][r] + bz);
  }
  __syncthreads();
  size_t so = (size_t)(b * FREQ + f) * SLICE;
#pragma unroll
  for (int i = 0; i < 2; ++i) {
    int q = tid + i * 256;
    int r = q >> 3, c = (q & 7) * 8;
    uint4 v = *(uint4*)&wB[r * 72 + c];
    *(uint4*)&resb[so + (size_t)(v0 + r) * 64 + c] = v;
    if (f >= 31) {
      size_t co = ((size_t)b * MAXK + (f - 31)) * SLICE + (size_t)(v0 + r) * 64 + c;
      *(uint4*)&curb[co] = v;
      bf16 tmp[8];
      *(uint4*)tmp = v;
      float4 fa, fb;
      fa.x = (float)tmp[0]; fa.y = (float)tmp[1]; fa.z = (float)tmp[2]; fa.w = (float)tmp[3];
      fb.x = (float)tmp[4]; fb.y = (float)tmp[5]; fb.z = (float)tmp[6]; fb.w = (float)tmp[7];
      *(float4*)&cur[co] = fa;
      *(float4*)&cur[co + 4] = fb;
    }
  }
}

// ---------------- staging helpers ----------------
__device__ __forceinline__ void stageA(bf16* lds_a, const bf16* src, int rowStride, int tid) {
#pragma unroll
  for (int i = 0; i < 8; ++i) {
    int q = tid + i * 256;
    int r = q >> 3, c = (q & 7) << 3;
    *(uint4*)&lds_a[r * 72 + c] = *(const uint4*)&src[(size_t)r * rowStride + c];
  }
}
__device__ __forceinline__ void stageB(bf16* lds_b, const bf16* src, int rowStride, int tid) {
#pragma unroll
  for (int i = 0; i < 2; ++i) {
    int q = tid + i * 256;
    int r = q >> 3, c = (q & 7) << 3;
    *(uint4*)&lds_b[r * 72 + c] = *(const uint4*)&src[(size_t)r * rowStride + c];
  }
}
__device__ __forceinline__ void mfma64(const bf16* lds_a, const bf16* lds_b, int wid, int lane,
                                       f32x4 acc[4][4]) {
  int lr = lane & 15, lg = lane >> 4;
#pragma unroll
  for (int h = 0; h < 2; ++h) {
    bf16x8 af[4], bfr[4];
#pragma unroll
    for (int mi = 0; mi < 4; ++mi)
      af[mi] = *(const bf16x8*)&lds_a[(wid * 64 + mi * 16 + lr) * 72 + h * 32 + lg * 8];
#pragma unroll
    for (int ni = 0; ni < 4; ++ni)
      bfr[ni] = *(const bf16x8*)&lds_b[(ni * 16 + lr) * 72 + h * 32 + lg * 8];
#pragma unroll
    for (int mi = 0; mi < 4; ++mi)
#pragma unroll
      for (int ni = 0; ni < 4; ++ni)
        acc[mi][ni] =
            __builtin_amdgcn_mfma_f32_16x16x32_bf16(af[mi], bfr[ni], acc[mi][ni], 0, 0, 0);
  }
}

// ---------------- A^2 precompute ----------------
__global__ __launch_bounds__(256) void asq_k(const bf16* __restrict__ a,
                                             const bf16* __restrict__ aT,
                                             bf16* __restrict__ out) {
  __shared__ __align__(16) bf16 As[64 * 72];
  __shared__ __align__(16) bf16 Bs2[64 * 72];
  int tid = threadIdx.x, w = tid >> 6, lane = tid & 63;
  int lr = lane & 15, lg = lane >> 4;
  int v0 = blockIdx.x * 64, n0 = blockIdx.y * 64;
  f32x4 acc[4] = {};
  for (int k0 = 0; k0 < 1024; k0 += 64) {
    __syncthreads();
    stageB(As, a + (size_t)v0 * 1024 + k0, 1024, tid);
    stageB(Bs2, aT + (size_t)n0 * 1024 + k0, 1024, tid);
    __syncthreads();
#pragma unroll
    for (int h = 0; h < 2; ++h) {
      bf16x8 av = *(const bf16x8*)&As[(w * 16 + lr) * 72 + h * 32 + lg * 8];
#pragma unroll
      for (int ni = 0; ni < 4; ++ni) {
        bf16x8 bv = *(const bf16x8*)&Bs2[(ni * 16 + lr) * 72 + h * 32 + lg * 8];
        acc[ni] = __builtin_amdgcn_mfma_f32_16x16x32_bf16(av, bv, acc[ni], 0, 0, 0);
      }
    }
  }
#pragma unroll
  for (int ni = 0; ni < 4; ++ni)
#pragma unroll
    for (int r = 0; r < 4; ++r) As[(w * 16 + lg * 4 + r) * 72 + ni * 16 + lr] = (bf16)acc[ni][r];
  __syncthreads();
#pragma unroll
  for (int i = 0; i < 2; ++i) {
    int q = tid + i * 256;
    int r = q >> 3, c = (q & 7) * 8;
    *(uint4*)&out[(size_t)(v0 + r) * 1024 + n0 + c] = *(uint4*)&As[r * 72 + c];
  }
}

// ---------------- inception (rec): LDS-staged (round-10 grid: x=tile, y=slice) ----------------
__global__ __launch_bounds__(256) void incep_k(const bf16* __restrict__ resb, int b0,
                                               const bf16* __restrict__ Wc,
                                               const float* __restrict__ bsum,
                                               bf16* __restrict__ xcN, bf16* __restrict__ xcF) {
  __shared__ __align__(16) bf16 lds_a[256 * 72];
  __shared__ __align__(16) bf16 lds_b[64 * 72];
  int tid = threadIdx.x, wid = tid >> 6, lane = tid & 63;
  int v0 = blockIdx.x * 256;
  int sl = blockIdx.y;
  int b = b0 + sl / TREC, tt = sl % TREC;
  f32x4 acc[4][4] = {};
  for (int dt = 0; dt < MAXK; ++dt) {
    int ts = tt + dt - 5;
    if (ts < 0 || ts >= TREC) continue;
    __syncthreads();
    stageA(lds_a, resb + (size_t)(b * FREQ + ts) * SLICE + (size_t)v0 * 64, 64, tid);
    stageB(lds_b, Wc + dt * 4096, 64, tid);
    __syncthreads();
    mfma64(lds_a, lds_b, wid, lane, acc);
  }
  int lr = lane & 15, lg = lane >> 4;
  size_t so = (size_t)sl * SLICE;
  __syncthreads();
#pragma unroll
  for (int mi = 0; mi < 4; ++mi)
#pragma unroll
    for (int ni = 0; ni < 4; ++ni) {
      int n = ni * 16 + lr;
      float bs = bsum[n];
      union { bf16 h[4]; uint2 u; } pk;
#pragma unroll
      for (int r = 0; r < 4; ++r) {
        int m = wid * 64 + mi * 16 + lg * 4 + r;
        bf16 bv = (bf16)((acc[mi][ni][r] + bs) * (1.f / 6.f));
        lds_a[m * 72 + n] = bv;
        pk.h[r] = bv;
      }
      *(uint2*)&xcF[so + (size_t)n * 1024 + v0 + wid * 64 + mi * 16 + lg * 4] = pk.u;
    }
  __syncthreads();
#pragma unroll
  for (int i = 0; i < 8; ++i) {
    int q = tid + i * 256;
    int r = q >> 3, c = (q & 7) * 8;
    *(uint4*)&xcN[so + (size_t)(v0 + r) * 64 + c] = *(uint4*)&lds_a[r * 72 + c];
  }
}

// ---------------- fused rec (round-10: grid x=tile(16), y=slice; 55 KB LDS) ----------------
__global__ __launch_bounds__(256) void fusedrec_k(
    const bf16* __restrict__ xcN, const bf16* __restrict__ xcF, const bf16* __restrict__ a1,
    const bf16* __restrict__ a1q, const bf16* __restrict__ a2, const bf16* __restrict__ a2q,
    const bf16* __restrict__ Vt, const float* __restrict__ gbsum,
    const bf16* __restrict__ resb, int b0, const bf16* __restrict__ dw1T,
    const float* __restrict__ db1, const bf16* __restrict__ dw2T,
    const float* __restrict__ db2, float* __restrict__ outRec) {
  __shared__ __align__(16) bf16 reg1[4][64 * 72];
  __shared__ __align__(16) bf16 reg2[64 * 72];
  __shared__ __align__(16) bf16 valb[64 * 72];
  bf16* hb = &reg1[0][0];
  int tid = threadIdx.x, w = tid >> 6, lane = tid & 63;
  int lr = lane & 15, lg = lane >> 4;
  int v0 = blockIdx.x * 64;
  int sy = blockIdx.y;
  int bl = sy / FREQ, f = sy % FREQ;
  int b = b0 + bl;

  if (f == 0) {
    const bf16* src = resb + (size_t)(b * FREQ) * SLICE + (size_t)v0 * 64;
#pragma unroll
    for (int i = 0; i < 2; ++i) {
      int q = tid + i * 256;
      int r = q >> 3, c = (q & 7) * 8;
      *(uint4*)&valb[r * 72 + c] = *(const uint4*)&src[(size_t)r * 64 + c];
    }
    __syncthreads();
  } else {
    int tt = f - 1;
    size_t so = (size_t)(bl * TREC + tt) * SLICE;
    f32x4 acc[4][4] = {};
    for (int k0 = 0; k0 < 1024; k0 += 64) {
      __syncthreads();
#pragma unroll
      for (int i = 0; i < 8; ++i) {
        int q = tid + i * 256;
        int mm = q >> 9, pos = q & 511;
        int rr = pos >> 3, cc = (pos & 7) * 8;
        const bf16* mp = mm == 0 ? a1 : (mm == 1 ? a1q : (mm == 2 ? a2 : a2q));
        *(uint4*)&reg1[mm][rr * 72 + cc] = *(const uint4*)&mp[(size_t)(v0 + rr) * 1024 + k0 + cc];
      }
#pragma unroll
      for (int i = 0; i < 2; ++i) {
        int q = tid + i * 256;
        int rb = q >> 3, cbb = (q & 7) * 8;
        *(uint4*)&reg2[rb * 72 + cbb] = *(const uint4*)&xcF[so + (size_t)rb * 1024 + k0 + cbb];
      }
      __syncthreads();
#pragma unroll
      for (int h = 0; h < 2; ++h) {
        bf16x8 af[4], bfr[4];
#pragma unroll
        for (int mi = 0; mi < 4; ++mi)
          af[mi] = *(const bf16x8*)&reg1[w][(mi * 16 + lr) * 72 + h * 32 + lg * 8];
#pragma unroll
        for (int ni = 0; ni < 4; ++ni)
          bfr[ni] = *(const bf16x8*)&reg2[(ni * 16 + lr) * 72 + h * 32 + lg * 8];
#pragma unroll
        for (int mi = 0; mi < 4; ++mi)
#pragma unroll
          for (int ni = 0; ni < 4; ++ni)
            acc[mi][ni] =
                __builtin_amdgcn_mfma_f32_16x16x32_bf16(af[mi], bfr[ni], acc[mi][ni], 0, 0, 0);
      }
    }
    __syncthreads();
#pragma unroll
    for (int mi = 0; mi < 4; ++mi)
#pragma unroll
      for (int ni = 0; ni < 4; ++ni)
#pragma unroll
        for (int r = 0; r < 4; ++r)
          reg1[w][(mi * 16 + lg * 4 + r) * 72 + ni * 16 + lr] = (bf16)acc[mi][ni][r];
#pragma unroll
    for (int i = 0; i < 2; ++i) {
      int q = tid + i * 256;
      int r = q >> 3, c = (q & 7) * 8;
      *(uint4*)&reg2[r * 72 + c] = *(const uint4*)&xcN[so + (size_t)(v0 + r) * 64 + c];
    }
    __syncthreads();
    f32x4 z[4] = {};
#pragma unroll
    for (int j = 0; j < 5; ++j) {
      const bf16* Asrc = (j == 0) ? reg2 : &reg1[j - 1][0];
#pragma unroll
      for (int h = 0; h < 2; ++h) {
        bf16x8 a = *(const bf16x8*)&Asrc[(w * 16 + lr) * 72 + h * 32 + lg * 8];
#pragma unroll
        for (int ni = 0; ni < 4; ++ni) {
          bf16x8 bb =
              *(const bf16x8*)&Vt[(size_t)j * 4096 + (ni * 16 + lr) * 64 + h * 32 + lg * 8];
          z[ni] = __builtin_amdgcn_mfma_f32_16x16x32_bf16(a, bb, z[ni], 0, 0, 0);
        }
      }
    }
    const bf16* xb = resb + (size_t)(b * FREQ + tt) * SLICE + (size_t)v0 * 64;
#pragma unroll
    for (int ni = 0; ni < 4; ++ni) {
      int n = ni * 16 + lr;
      float gb = gbsum[n];
#pragma unroll
      for (int r = 0; r < 4; ++r) {
        int m = w * 16 + lg * 4 + r;
        valb[m * 72 + n] = (bf16)((float)xb[(size_t)m * 64 + n] + z[ni][r] + gb);
      }
    }
    __syncthreads();
  }
  // decoder layer1 (64->128 relu)
  f32x4 hacc[4][2] = {};
#pragma unroll
  for (int h = 0; h < 2; ++h) {
    bf16x8 a[4];
#pragma unroll
    for (int mi = 0; mi < 4; ++mi)
      a[mi] = *(const bf16x8*)&valb[(mi * 16 + lr) * 72 + h * 32 + lg * 8];
#pragma unroll
    for (int ni2 = 0; ni2 < 2; ++ni2) {
      bf16x8 bb = *(const bf16x8*)&dw1T[(w * 32 + ni2 * 16 + lr) * 64 + h * 32 + lg * 8];
#pragma unroll
      for (int mi = 0; mi < 4; ++mi)
        hacc[mi][ni2] = __builtin_amdgcn_mfma_f32_16x16x32_bf16(a[mi], bb, hacc[mi][ni2], 0, 0, 0);
    }
  }
  __syncthreads();
#pragma unroll
  for (int ni2 = 0; ni2 < 2; ++ni2) {
    int j = w * 32 + ni2 * 16 + lr;
    float bz = db1[j];
#pragma unroll
    for (int mi = 0; mi < 4; ++mi)
#pragma unroll
      for (int r = 0; r < 4; ++r)
        hb[(mi * 16 + lg * 4 + r) * 136 + j] = (bf16)fmaxf(hacc[mi][ni2][r] + bz, 0.f);
  }
  __syncthreads();
  // layer2 (128->8)
  f32x4 oacc = {};
#pragma unroll
  for (int kc = 0; kc < 4; ++kc) {
    bf16x8 a = *(const bf16x8*)&hb[(w * 16 + lr) * 136 + kc * 32 + lg * 8];
    bf16x8 bb = *(const bf16x8*)&dw2T[lr * 128 + kc * 32 + lg * 8];
    oacc = __builtin_amdgcn_mfma_f32_16x16x32_bf16(a, bb, oacc, 0, 0, 0);
  }
  if (lr < 8) {
    float bz = db2[lr];
    float4 o;
    o.x = oacc[0] + bz;
    o.y = oacc[1] + bz;
    o.z = oacc[2] + bz;
    o.w = oacc[3] + bz;
    *(float4*)&outRec[(size_t)b * 344064 + (size_t)(f * 8 + lr) * 1024 + v0 + w * 16 + lg * 4] =
        o;
  }
}

// ---------------- AR branch v6 (round-10: b = bid>>6) ----------------
__device__ __forceinline__ void arrive_wait(unsigned* c, int tid) {
  __syncthreads();
  if (tid == 0) {
    __hip_atomic_fetch_add(c, 1u, __ATOMIC_RELAXED, __HIP_MEMORY_SCOPE_AGENT);
    while (__hip_atomic_load(c, __ATOMIC_RELAXED, __HIP_MEMORY_SCOPE_AGENT) < 64u)
      __builtin_amdgcn_s_sleep(8);
  }
  __syncthreads();
}

__device__ __forceinline__ void incep16(const bf16* __restrict__ curb,
                                        const bf16* __restrict__ Wc, const float* bsums_,
                                        int base, int b, int r0, int w, int lr, int lg,
                                        bf16* yL, bf16* yFdst) {
  f32x4 ya = {};
  for (int j = 0; j < 6; ++j) {
    int slot = (base + 5 + j) % MAXK;
    const bf16* cb = curb + ((size_t)b * MAXK + slot) * SLICE + (size_t)r0 * 64;
#pragma unroll
    for (int h = 0; h < 2; ++h) {
      bf16x8 a = *(const bf16x8*)&cb[lr * 64 + h * 32 + lg * 8];
      bf16x8 bb = *(const bf16x8*)&Wc[(size_t)j * 4096 + (w * 16 + lr) * 64 + h * 32 + lg * 8];
      ya = __builtin_amdgcn_mfma_f32_16x16x32_bf16(a, bb, ya, 0, 0, 0);
    }
  }
  int n = w * 16 + lr;
  float bs = bsums_[n];
  union { bf16 h[4]; unsigned long long u; } pk;
#pragma unroll
  for (int r = 0; r < 4; ++r) {
    int m = lg * 4 + r;
    bf16 bv = (bf16)((ya[r] + bs) * (1.f / 6.f));
    yL[m * 72 + n] = bv;
    pk.h[r] = bv;
  }
  __hip_atomic_store((unsigned long long*)(yFdst + (size_t)n * 1024 + r0 + lg * 4), pk.u,
                     __ATOMIC_RELAXED, __HIP_MEMORY_SCOPE_AGENT);
}

struct AR5 {
  const bf16 *Wc;
  const float *bsum;
  const bf16 *a1, *a1q, *a2, *a2q;
  const bf16 *Vt;
  const float *gbsum;
  float *cur;
  bf16 *curb;
  bf16 *yF;
  const bf16 *dw1T;
  const float *db1;
  const bf16 *dw2T;
  const float *db2;
  float *outPred;
  unsigned *bar;
};

__global__ void __launch_bounds__(256) ar6_k(AR5 p) {
  __shared__ __align__(16) bf16 As4[2][4][16 * 72];
  __shared__ __align__(16) bf16 Bs[2][64 * 72];
  __shared__ __align__(16) bf16 yL[16 * 72];
  __shared__ __align__(16) bf16 PL[4][16 * 72];
  __shared__ __align__(16) bf16 valb[16 * 72];
  __shared__ __align__(16) bf16 hb[16 * 136];
  __shared__ float db1s[128], db2s[8], bsums[64], gbsums[64];
  int tid = threadIdx.x, w = tid >> 6, lane = tid & 63;
  int lr = lane & 15, lg = lane >> 4;
  int bid = blockIdx.x, b = bid >> 6, l = bid & 63;
  unsigned* cnt = p.bar + b * 32;
  int r0 = l * 16;

  if (tid < 128) db1s[tid] = p.db1[tid];
  if (tid < 8) db2s[tid] = p.db2[tid];
  if (tid < 64) {
    bsums[tid] = p.bsum[tid];
    gbsums[tid] = p.gbsum[tid];
  }
  __syncthreads();

  incep16(p.curb, p.Wc, bsums, 0, b, r0, w, lr, lg, yL, p.yF + (size_t)b * SLICE);
  arrive_wait(cnt + 0, tid);

  const bf16* mats[4] = {p.a1, p.a1q, p.a2, p.a2q};
  for (int s = 0; s < NSTEP; ++s) {
    {
      const bf16* yFs = p.yF + ((size_t)s * NB + b) * SLICE;
      f32x4 acc[4] = {};
      auto stage_chunk = [&](int d, int k0) {
#pragma unroll
        for (int i = 0; i < 2; ++i) {
          int q = tid + i * 256;
          int mm = q >> 7, rr = (q >> 3) & 15, cc = (q & 7) * 8;
          *(uint4*)&As4[d][mm][rr * 72 + cc] =
              *(const uint4*)&mats[mm][(size_t)(r0 + rr) * 1024 + k0 + cc];
          int rb = q >> 3, cb2 = (q & 7) * 8;
          *(uint4*)&Bs[d][rb * 72 + cb2] = *(const uint4*)&yFs[(size_t)rb * 1024 + k0 + cb2];
        }
      };
      stage_chunk(0, 0);
      for (int c = 0; c < 16; ++c) {
        __syncthreads();
        if (c < 15) stage_chunk((c + 1) & 1, (c + 1) * 64);
#pragma unroll
        for (int h = 0; h < 2; ++h) {
          bf16x8 a = *(const bf16x8*)&As4[c & 1][w][lr * 72 + h * 32 + lg * 8];
#pragma unroll
          for (int ni = 0; ni < 4; ++ni) {
            bf16x8 bb = *(const bf16x8*)&Bs[c & 1][(ni * 16 + lr) * 72 + h * 32 + lg * 8];
            acc[ni] = __builtin_amdgcn_mfma_f32_16x16x32_bf16(a, bb, acc[ni], 0, 0, 0);
          }
        }
      }
#pragma unroll
      for (int ni = 0; ni < 4; ++ni) {
        int nn = ni * 16 + lr;
#pragma unroll
        for (int r = 0; r < 4; ++r) PL[w][(lg * 4 + r) * 72 + nn] = (bf16)acc[ni][r];
      }
    }
    __syncthreads();
    {
      f32x4 z = {};
#pragma unroll
      for (int j = 0; j < 5; ++j) {
        const bf16* Aj = (j == 0) ? yL : PL[j - 1];
#pragma unroll
        for (int h = 0; h < 2; ++h) {
          bf16x8 a = *(const bf16x8*)&Aj[lr * 72 + h * 32 + lg * 8];
          bf16x8 bb =
              *(const bf16x8*)&p.Vt[(size_t)j * 4096 + (w * 16 + lr) * 64 + h * 32 + lg * 8];
          z = __builtin_amdgcn_mfma_f32_16x16x32_bf16(a, bb, z, 0, 0, 0);
        }
      }
      int slotR = (s + 10) % MAXK, slotW = s % MAXK;
      size_t xo = ((size_t)b * MAXK + slotR) * SLICE + (size_t)r0 * 64;
      size_t wo = ((size_t)b * MAXK + slotW) * SLICE + (size_t)r0 * 64;
      int n = w * 16 + lr;
      float gb = gbsums[n];
#pragma unroll
      for (int r = 0; r < 4; ++r) {
        int m = lg * 4 + r;
        size_t o = (size_t)m * 64 + n;
        float v = p.cur[xo + o] + z[r] + gb;
        p.cur[wo + o] = v;
        p.curb[wo + o] = (bf16)v;
        valb[m * 72 + n] = (bf16)v;
      }
      __syncthreads();
      if (s < NSTEP - 1)
        incep16(p.curb, p.Wc, bsums, s + 1, b, r0, w, lr, lg, yL,
                p.yF + ((size_t)(s + 1) * NB + b) * SLICE);
      f32x4 hacc[2] = {};
#pragma unroll
      for (int h = 0; h < 2; ++h) {
        bf16x8 a = *(const bf16x8*)&valb[lr * 72 + h * 32 + lg * 8];
#pragma unroll
        for (int ni2 = 0; ni2 < 2; ++ni2) {
          bf16x8 bb = *(const bf16x8*)&p.dw1T[(w * 32 + ni2 * 16 + lr) * 64 + h * 32 + lg * 8];
          hacc[ni2] = __builtin_amdgcn_mfma_f32_16x16x32_bf16(a, bb, hacc[ni2], 0, 0, 0);
        }
      }
#pragma unroll
      for (int ni2 = 0; ni2 < 2; ++ni2) {
        int j = w * 32 + ni2 * 16 + lr;
        float bz = db1s[j];
#pragma unroll
        for (int r = 0; r < 4; ++r)
          hb[(lg * 4 + r) * 136 + j] = (bf16)fmaxf(hacc[ni2][r] + bz, 0.f);
      }
      __syncthreads();
      f32x4 oacc = {};
#pragma unroll
      for (int kc = 0; kc < 4; ++kc) {
        bf16x8 a = *(const bf16x8*)&hb[lr * 136 + kc * 32 + lg * 8];
        bf16x8 bb = *(const bf16x8*)&p.dw2T[lr * 128 + kc * 32 + lg * 8];
        oacc = __builtin_amdgcn_mfma_f32_16x16x32_bf16(a, bb, oacc, 0, 0, 0);
      }
      if (w == 0 && lr < 8) {
        float bz = db2s[lr];
#pragma unroll
        for (int r = 0; r < 4; ++r)
          p.outPred[(size_t)b * 98304 + (size_t)s * 8192 + (size_t)(r0 + lg * 4 + r) * 8 + lr] =
              oacc[r] + bz;
      }
    }
    if (s < NSTEP - 1) arrive_wait(cnt + 1 + s, tid);
  }
}

// ---------------- host launch ----------------
extern "C" void kernel_launch(void* const* d_in, const int* in_sizes, int n_in, void* d_out,
                              int out_size, void* d_ws, size_t ws_size, hipStream_t stream) {
  const float* x_diff = (const float*)d_in[0];
  const float* adj = (const float*)d_in[1];
  const float* enc_w1 = (const float*)d_in[2];
  const float* enc_b1 = (const float*)d_in[3];
  const float* enc_w2 = (const float*)d_in[4];
  const float* enc_b2 = (const float*)d_in[5];
  const float* dec_w1 = (const float*)d_in[6];
  const float* dec_b1 = (const float*)d_in[7];
  const float* dec_w2 = (const float*)d_in[8];
  const float* dec_b2 = (const float*)d_in[9];
  const float* g1_w = (const float*)d_in[10];
  const float* g1_b = (const float*)d_in[11];
  const float* g2_w = (const float*)d_in[12];
  const float* g2_b = (const float*)d_in[13];
  const float* cw[6];
  const float* cb_[6];
  for (int i = 0; i < 6; ++i) {
    cw[i] = (const float*)d_in[14 + 2 * i];
    cb_[i] = (const float*)d_in[15 + 2 * i];
  }

  char* base = (char*)d_ws;
  size_t off = 0;
  auto alloc = [&](size_t bytes) -> void* {
    void* p = base + off;
    off = (off + bytes + 255) & ~(size_t)255;
    return p;
  };
  float* adjT = (float*)alloc(1048576ULL * 4);
  float* rowsum = (float*)alloc(4096);
  float* colsum = (float*)alloc(4096);
  bf16* a1b = (bf16*)alloc(1048576ULL * 2);
  bf16* a2b = (bf16*)alloc(1048576ULL * 2);
  bf16* a1T = (bf16*)alloc(1048576ULL * 2);
  bf16* a2T = (bf16*)alloc(1048576ULL * 2);
  bf16* a1q = (bf16*)alloc(1048576ULL * 2);
  bf16* a2q = (bf16*)alloc(1048576ULL * 2);
  bf16* Wc = (bf16*)alloc(45056ULL * 2);
  float* bsum = (float*)alloc(256);
  float* gbsum = (float*)alloc(256);
  bf16* Vt = (bf16*)alloc(20480ULL * 2);
  bf16* w2T = (bf16*)alloc(8192ULL * 2);
  bf16* dw1T = (bf16*)alloc(8192ULL * 2);
  bf16* dw2T = (bf16*)alloc(2048ULL * 2);
  bf16* resb = (bf16*)alloc((size_t)NB * FREQ * SLICE * 2);
  float* cur = (float*)alloc((size_t)NB * MAXK * SLICE * 4);
  bf16* curb = (bf16*)alloc((size_t)NB * MAXK * SLICE * 2);
  bf16* yF = (bf16*)alloc((size_t)NSTEP * NB * SLICE * 2);
  unsigned* gbar = (unsigned*)alloc(4096);
  size_t fixedEnd = off;
  int cb = NB;
  while (cb > 1) {
    size_t S = (size_t)TREC * cb;
    if (fixedEnd + S * SLICE * 4 + 65536 <= ws_size) break;
    cb >>= 1;
  }
  size_t S = (size_t)TREC * cb;
  bf16* xcN = (bf16*)alloc(S * SLICE * 2);
  bf16* xcF = (bf16*)alloc(S * SLICE * 2);

  float* outF = (float*)d_out;
  float* outRec = outF;
  float* outPred = outF + (size_t)2752512;

  transpose_k<<<dim3(32, 32), dim3(32, 8), 0, stream>>>(adj, adjT);
  rowsum_k<<<1024, 256, 0, stream>>>(adj, rowsum);
  rowsum_k<<<1024, 256, 0, stream>>>(adjT, colsum);
  norm_k<<<2048, 256, 0, stream>>>(adj, adjT, rowsum, colsum, a1b, a2b);
  btrans_k<<<dim3(16, 16), 256, 0, stream>>>(a1b, a1T);
  btrans_k<<<dim3(16, 16), 256, 0, stream>>>(a2b, a2T);
  asq_k<<<dim3(16, 16), 256, 0, stream>>>(a1b, a1T, a1q);
  asq_k<<<dim3(16, 16), 256, 0, stream>>>(a2b, a2T, a2q);
  combine_w_k<<<(MAXK * 4096 + 255) / 256, 256, 0, stream>>>(cw[0], cw[1], cw[2], cw[3], cw[4],
                                                             cw[5], cb_[0], cb_[1], cb_[2],
                                                             cb_[3], cb_[4], cb_[5], Wc, bsum);
  vt_k<<<80, 256, 0, stream>>>(g1_w, g2_w, g1_b, g2_b, Vt, gbsum);
  prep_misc_k<<<32, 256, 0, stream>>>(enc_w2, dec_w1, dec_w2, w2T, dw1T, dw2T);
  encoder_k<<<dim3(16, NB * FREQ), 256, 0, stream>>>(x_diff, enc_w1, enc_b1, w2T, enc_b2,
                                                     resb, cur, curb);

  // ---- reconstruction branch (round-10 grids) ----
  for (int c0 = 0; c0 < NB; c0 += cb) {
    int Sg = TREC * cb;
    incep_k<<<dim3(4, Sg), 256, 0, stream>>>(resb, c0, Wc, bsum, xcN, xcF);
    fusedrec_k<<<dim3(16, cb * FREQ), 256, 0, stream>>>(xcN, xcF, a1b, a1q, a2b, a2q, Vt,
                                                        gbsum, resb, c0, dw1T, dec_b1, dw2T,
                                                        dec_b2, outRec);
  }

  // ---- autoregressive branch ----
  hipMemsetAsync(gbar, 0, 4096, stream);
  AR5 arp;
  arp.Wc = Wc; arp.bsum = bsum;
  arp.a1 = a1b; arp.a1q = a1q; arp.a2 = a2b; arp.a2q = a2q;
  arp.Vt = Vt; arp.gbsum = gbsum;
  arp.cur = cur; arp.curb = curb;
  arp.yF = yF;
  arp.dw1T = dw1T; arp.db1 = dec_b1; arp.dw2T = dw2T; arp.db2 = dec_b2;
  arp.outPred = outPred;
  arp.bar = gbar;
  ar6_k<<<dim3(512), dim3(256), 0, stream>>>(arp);
}